// Round 1
// baseline (1034.086 us; speedup 1.0000x reference)
//
#include <hip/hip_runtime.h>
#include <cstdint>
#include <cstddef>

#define BB 8
#define SS 1024
#define HH 768
#define TT 8
#define DII 64
#define HIDD 128
#define KSP 8
#define NHEADS 2
#define NNODES 9
#define GDIM 256   // NHEADS*HIDD
#define CDIM 1024  // TT*2*DII == HH+GDIM
#define DAUG 80    // DII + 16 gaussian-aug dims
#define NEGV 1e12f

// ---------------- K1: nodes (global mean + span means) and cover ----------------
__global__ void k1_nodes(const float* __restrict__ hidden, const int* __restrict__ spans,
                         float* __restrict__ nodes, float* __restrict__ cover) {
  int b = blockIdx.x, tid = threadIdx.x;
  __shared__ int sp[KSP * 3];
  if (tid < KSP * 3) sp[tid] = spans[b * KSP * 3 + tid];
  __syncthreads();
  for (int s = tid; s < SS; s += 256) {
    float c = 0.f;
    #pragma unroll
    for (int k = 0; k < KSP; k++)
      c += (s >= sp[k * 3] && s <= sp[k * 3 + 1]) ? 1.f : 0.f;
    cover[b * SS + s] = c;
  }
  const float* hb = hidden + (size_t)b * SS * HH;
  for (int c0 = tid; c0 < HH; c0 += 256) {
    float acc = 0.f;
    for (int s = 0; s < SS; s++) acc += hb[(size_t)s * HH + c0];
    nodes[((size_t)b * NNODES + 0) * HH + c0] = acc / (float)SS;
    for (int k = 0; k < KSP; k++) {
      int st = sp[k * 3], en = sp[k * 3 + 1];
      float a2 = 0.f;
      for (int s = st; s <= en; s++) a2 += hb[(size_t)s * HH + c0];
      nodes[((size_t)b * NNODES + (k + 1)) * HH + c0] = a2 / (float)(en - st + 1);
    }
  }
}

// ---------------- K2: two GAT layers + LN -> enhanced -> E2 = enh @ W_bot --------
__global__ __launch_bounds__(256) void k2_gat(
    const float* __restrict__ nodes_g, const int* __restrict__ spans,
    const float* __restrict__ W1, const float* __restrict__ a_src1,
    const float* __restrict__ a_dst1, const float* __restrict__ b1,
    const float* __restrict__ ln_g, const float* __restrict__ ln_b,
    const float* __restrict__ W2, const float* __restrict__ a_src2,
    const float* __restrict__ a_dst2, const float* __restrict__ b2,
    const float* __restrict__ dense_W, float* __restrict__ E2) {
  int b = blockIdx.x, tid = threadIdx.x;
  __shared__ float nod[NNODES * HH];
  __shared__ float hbuf[NNODES * GDIM];
  __shared__ float gbuf[NNODES * GDIM];
  __shared__ float asrc[NNODES * NHEADS], adst[NNODES * NHEADS];
  __shared__ float adjm[NNODES * NNODES];
  __shared__ float attn[NNODES * NNODES * NHEADS];
  __shared__ float mu_s[NNODES], rs_s[NNODES];
  __shared__ float enh[GDIM];
  __shared__ int sp[KSP * 3];
  if (tid < KSP * 3) sp[tid] = spans[b * KSP * 3 + tid];
  for (int i = tid; i < NNODES * HH; i += 256)
    nod[i] = nodes_g[(size_t)b * NNODES * HH + i];
  __syncthreads();
  // h = nodes @ W1   (each thread owns output column tid)
  {
    float acc[NNODES];
    #pragma unroll
    for (int n = 0; n < NNODES; n++) acc[n] = 0.f;
    for (int d = 0; d < HH; d++) {
      float w = W1[(size_t)d * GDIM + tid];
      #pragma unroll
      for (int n = 0; n < NNODES; n++) acc[n] += nod[n * HH + d] * w;
    }
    #pragma unroll
    for (int n = 0; n < NNODES; n++) hbuf[n * GDIM + tid] = acc[n];
  }
  // adj
  if (tid < NNODES * NNODES) {
    int i = tid / NNODES, j = tid % NNODES;
    float a = (i == j) ? 1.f : 0.f;
    if (i > 0 && j == 0) a += 1.f;
    if (i == 0 && j > 0) a += 1.f;
    if (i > 0 && j > 0 && i != j) {
      int x = j - 1, y = i - 1;
      int sx = sp[x * 3], ex = sp[x * 3 + 1], sy = sp[y * 3], ey = sp[y * 3 + 1];
      bool same = (sx == sy) && (ex == ey);
      if (sx <= sy && ey <= ex && !same) a += 2.f;
    }
    adjm[tid] = a;
  }
  __syncthreads();
  // asrc/adst layer1
  if (tid < NNODES * NHEADS) {
    int n = tid >> 1, hd = tid & 1;
    float sa = 0.f, sd = 0.f;
    for (int f = 0; f < HIDD; f++) {
      float v = hbuf[n * GDIM + hd * HIDD + f];
      sa += v * a_src1[hd * HIDD + f];
      sd += v * a_dst1[hd * HIDD + f];
    }
    asrc[tid] = sa; adst[tid] = sd;
  }
  __syncthreads();
  // attn layer1
  if (tid < NNODES * NHEADS) {
    int d = tid >> 1, hd = tid & 1;
    float sc[NNODES]; float mx = -1e30f;
    for (int s2 = 0; s2 < NNODES; s2++) {
      float a = adjm[d * NNODES + s2]; float v;
      if (a > 0.f) {
        float e = adst[d * 2 + hd] + asrc[s2 * 2 + hd];
        e = (e > 0.f) ? e : 0.2f * e;
        v = e + __logf(a);
      } else v = -1e30f;
      sc[s2] = v; mx = fmaxf(mx, v);
    }
    float ssum = 0.f;
    for (int s2 = 0; s2 < NNODES; s2++) { float ex = __expf(sc[s2] - mx); sc[s2] = ex; ssum += ex; }
    float inv = 1.f / ssum;
    for (int s2 = 0; s2 < NNODES; s2++) attn[(d * NNODES + s2) * NHEADS + hd] = sc[s2] * inv;
  }
  __syncthreads();
  // out1 + relu
  {
    int hd = tid >> 7;
    float bb = b1[tid];
    for (int d = 0; d < NNODES; d++) {
      float acc = bb;
      #pragma unroll
      for (int s2 = 0; s2 < NNODES; s2++)
        acc += attn[(d * NNODES + s2) * NHEADS + hd] * hbuf[s2 * GDIM + tid];
      gbuf[d * GDIM + tid] = fmaxf(acc, 0.f);
    }
  }
  __syncthreads();
  // LN stats
  if (tid < NNODES) {
    float s1 = 0.f, s2v = 0.f;
    for (int o = 0; o < GDIM; o++) { float v = gbuf[tid * GDIM + o]; s1 += v; s2v += v * v; }
    float mu = s1 / (float)GDIM;
    float var = s2v / (float)GDIM - mu * mu;
    mu_s[tid] = mu; rs_s[tid] = rsqrtf(var + 1e-5f);
  }
  __syncthreads();
  {
    float g = ln_g[tid], bt = ln_b[tid];
    for (int d = 0; d < NNODES; d++)
      gbuf[d * GDIM + tid] = (gbuf[d * GDIM + tid] - mu_s[d]) * rs_s[d] * g + bt;
  }
  __syncthreads();
  // h2 = g1 @ W2
  {
    float acc[NNODES];
    #pragma unroll
    for (int n = 0; n < NNODES; n++) acc[n] = 0.f;
    for (int d = 0; d < GDIM; d++) {
      float w = W2[(size_t)d * GDIM + tid];
      #pragma unroll
      for (int n = 0; n < NNODES; n++) acc[n] += gbuf[n * GDIM + d] * w;
    }
    #pragma unroll
    for (int n = 0; n < NNODES; n++) hbuf[n * GDIM + tid] = acc[n];
  }
  __syncthreads();
  // asrc/adst layer2
  if (tid < NNODES * NHEADS) {
    int n = tid >> 1, hd = tid & 1;
    float sa = 0.f, sd = 0.f;
    for (int f = 0; f < HIDD; f++) {
      float v = hbuf[n * GDIM + hd * HIDD + f];
      sa += v * a_src2[hd * HIDD + f];
      sd += v * a_dst2[hd * HIDD + f];
    }
    asrc[tid] = sa; adst[tid] = sd;
  }
  __syncthreads();
  // attn layer2
  if (tid < NNODES * NHEADS) {
    int d = tid >> 1, hd = tid & 1;
    float sc[NNODES]; float mx = -1e30f;
    for (int s2 = 0; s2 < NNODES; s2++) {
      float a = adjm[d * NNODES + s2]; float v;
      if (a > 0.f) {
        float e = adst[d * 2 + hd] + asrc[s2 * 2 + hd];
        e = (e > 0.f) ? e : 0.2f * e;
        v = e + __logf(a);
      } else v = -1e30f;
      sc[s2] = v; mx = fmaxf(mx, v);
    }
    float ssum = 0.f;
    for (int s2 = 0; s2 < NNODES; s2++) { float ex = __expf(sc[s2] - mx); sc[s2] = ex; ssum += ex; }
    float inv = 1.f / ssum;
    for (int s2 = 0; s2 < NNODES; s2++) attn[(d * NNODES + s2) * NHEADS + hd] = sc[s2] * inv;
  }
  __syncthreads();
  // out2 + relu + node-mean -> enh
  {
    int hd = tid >> 7;
    float bb = b2[tid];
    float msum = 0.f;
    for (int d = 0; d < NNODES; d++) {
      float acc = bb;
      #pragma unroll
      for (int s2 = 0; s2 < NNODES; s2++)
        acc += attn[(d * NNODES + s2) * NHEADS + hd] * hbuf[s2 * GDIM + tid];
      msum += fmaxf(acc, 0.f);
    }
    enh[tid] = msum / 9.f;
  }
  __syncthreads();
  // E2[b][o] = enh . dense_W[768+d][o]
  for (int o = tid; o < CDIM; o += 256) {
    float acc = 0.f;
    for (int d = 0; d < GDIM; d++)
      acc += enh[d] * dense_W[(size_t)(HH + d) * CDIM + o];
    E2[b * CDIM + o] = acc;
  }
}

// ---------------- K3: qk = hidden @ W_top + cover*E2 + dense_b -------------------
__global__ __launch_bounds__(256) void k3_dense(
    const float* __restrict__ hidden, const float* __restrict__ dense_W,
    const float* __restrict__ dense_b, const float* __restrict__ cover,
    const float* __restrict__ E2, float* __restrict__ qk) {
  __shared__ float As[64 * 20];  // [m][k] pad 20
  __shared__ float Bs[16 * 64];  // [k][n]
  int tid = threadIdx.x;
  int n0 = blockIdx.x * 64, row0 = blockIdx.y * 64;
  int ty = tid >> 4, tx = tid & 15;
  float acc[4][4] = {};
  int lm = tid >> 2, lk = (tid & 3) * 4;
  int bk = tid >> 4, bn = (tid & 15) * 4;
  for (int k0 = 0; k0 < HH; k0 += 16) {
    float4 av = *(const float4*)&hidden[(size_t)(row0 + lm) * HH + k0 + lk];
    float4 bv = *(const float4*)&dense_W[(size_t)(k0 + bk) * CDIM + n0 + bn];
    __syncthreads();
    *(float4*)&As[lm * 20 + lk] = av;
    *(float4*)&Bs[bk * 64 + bn] = bv;
    __syncthreads();
    #pragma unroll
    for (int k = 0; k < 16; k++) {
      float a0 = As[(ty * 4 + 0) * 20 + k];
      float a1 = As[(ty * 4 + 1) * 20 + k];
      float a2 = As[(ty * 4 + 2) * 20 + k];
      float a3 = As[(ty * 4 + 3) * 20 + k];
      float4 bbv = *(const float4*)&Bs[k * 64 + tx * 4];
      acc[0][0] += a0 * bbv.x; acc[0][1] += a0 * bbv.y; acc[0][2] += a0 * bbv.z; acc[0][3] += a0 * bbv.w;
      acc[1][0] += a1 * bbv.x; acc[1][1] += a1 * bbv.y; acc[1][2] += a1 * bbv.z; acc[1][3] += a1 * bbv.w;
      acc[2][0] += a2 * bbv.x; acc[2][1] += a2 * bbv.y; acc[2][2] += a2 * bbv.z; acc[2][3] += a2 * bbv.w;
      acc[3][0] += a3 * bbv.x; acc[3][1] += a3 * bbv.y; acc[3][2] += a3 * bbv.z; acc[3][3] += a3 * bbv.w;
    }
  }
  #pragma unroll
  for (int i = 0; i < 4; i++) {
    int m = row0 + ty * 4 + i;
    int bidx = m >> 10;
    float cov = cover[m];
    float4 e2v = *(const float4*)&E2[bidx * CDIM + n0 + tx * 4];
    float4 dbv = *(const float4*)&dense_b[n0 + tx * 4];
    float4 o;
    o.x = acc[i][0] + cov * e2v.x + dbv.x;
    o.y = acc[i][1] + cov * e2v.y + dbv.y;
    o.z = acc[i][2] + cov * e2v.z + dbv.z;
    o.w = acc[i][3] + cov * e2v.w + dbv.w;
    *(float4*)&qk[(size_t)m * CDIM + n0 + tx * 4] = o;
  }
}

// ---------------- K4: RoPE + gaussian augment -> Qaug/Kaug (B,T,S,80) ------------
__global__ void k4_ropeaug(const float* __restrict__ qk, const int* __restrict__ spans,
                           const float* __restrict__ corr, const float* __restrict__ gc,
                           const float* __restrict__ gs, const float* __restrict__ gw,
                           float* __restrict__ Qa, float* __restrict__ Ka) {
  int idx = blockIdx.x * 256 + threadIdx.x;
  int d4 = idx % 20; int rest = idx / 20;
  int s = rest % SS; rest /= SS;
  int t = rest % TT; int b = rest / TT;
  float4 qv, kv;
  if (d4 < 16) {
    int d0 = d4 * 4;
    const float* row = qk + (size_t)(b * SS + s) * CDIM + t * 128;
    float4 q = *(const float4*)(row + d0);
    float4 k = *(const float4*)(row + 64 + d0);
    int i0 = d0 >> 1;
    const float LOG1E4_32 = 0.28782313662425576f;  // ln(10000)/32
    float inv0 = __expf(-(float)i0 * LOG1E4_32);
    float inv1 = __expf(-(float)(i0 + 1) * LOG1E4_32);
    float a0 = (float)s * inv0, a1 = (float)s * inv1;
    float c0, s0, c1, s1;
    __sincosf(a0, &s0, &c0);
    __sincosf(a1, &s1, &c1);
    qv.x = q.x * c0 - q.y * s0; qv.y = q.y * c0 + q.x * s0;
    qv.z = q.z * c1 - q.w * s1; qv.w = q.w * c1 + q.z * s1;
    kv.x = k.x * c0 - k.y * s0; kv.y = k.y * c0 + k.x * s0;
    kv.z = k.z * c1 - k.w * s1; kv.w = k.w * c1 + k.z * s1;
  } else {
    int j0 = (d4 - 16) * 4;
    float qq[4], kk[4];
    #pragma unroll
    for (int jj = 0; jj < 4; jj++) {
      int j = j0 + jj; int kp = j >> 1, c = j & 1;
      int st = spans[(b * KSP + kp) * 3 + 0];
      int en = spans[(b * KSP + kp) * 3 + 1];
      int et = spans[(b * KSP + kp) * 3 + 2];
      float sig = gs[c], w = gw[c], ce = gc[c];
      float cw = corr[et * TT + t];
      float dxs = ((float)s - (float)st - ce) / sig;
      float dxe = ((float)s - (float)en - ce) / sig;
      qq[jj] = cw * w * __expf(-0.5f * dxs * dxs);
      kk[jj] = w * __expf(-0.5f * dxe * dxe);
    }
    qv = make_float4(qq[0], qq[1], qq[2], qq[3]);
    kv = make_float4(kk[0], kk[1], kk[2], kk[3]);
  }
  size_t off = ((size_t)(b * TT + t) * SS + s) * DAUG + d4 * 4;
  *(float4*)(Qa + off) = qv;
  *(float4*)(Ka + off) = kv;
}

// ---------------- K5: logits = Qaug @ Kaug^T + mask epilogue ---------------------
__global__ __launch_bounds__(256) void k5_logits(
    const float* __restrict__ Qa, const float* __restrict__ Ka,
    const float* __restrict__ amask, float* __restrict__ out) {
  int bz = blockIdx.z; int b = bz >> 3;
  int n0 = blockIdx.x * 64, m0 = blockIdx.y * 64;
  int tid = threadIdx.x; int ty = tid >> 4, tx = tid & 15;
  if (n0 + 63 < m0) {
    // entire tile is strictly below the diagonal: value = (v*pad -(1-pad)NEG -NEG)/8,
    // |v|/8 << absmax threshold, write masked constant.
    int nb = n0 + tx * 4;
    float4 pv = *(const float4*)&amask[b * SS + nb];
    float4 o;
    o.x = (-(1.f - pv.x) * NEGV - NEGV) * 0.125f;
    o.y = (-(1.f - pv.y) * NEGV - NEGV) * 0.125f;
    o.z = (-(1.f - pv.z) * NEGV - NEGV) * 0.125f;
    o.w = (-(1.f - pv.w) * NEGV - NEGV) * 0.125f;
    #pragma unroll
    for (int i = 0; i < 4; i++) {
      int m = m0 + ty * 4 + i;
      *(float4*)&out[((size_t)bz * SS + m) * SS + nb] = o;
    }
    return;
  }
  __shared__ float Qs[DAUG * 68];  // [d][m] pad 68
  __shared__ float Ks[DAUG * 68];  // [d][n] pad 68
  const float* Qrow = Qa + ((size_t)bz * SS + m0) * DAUG;
  const float* Krow = Ka + ((size_t)bz * SS + n0) * DAUG;
  #pragma unroll
  for (int it = 0; it < 5; it++) {
    int f = tid + it * 256;          // 0..1279 float4s
    int r = f / 20, dq = (f % 20) * 4;
    float4 qv = *(const float4*)(Qrow + (size_t)r * DAUG + dq);
    float4 kv = *(const float4*)(Krow + (size_t)r * DAUG + dq);
    Qs[(dq + 0) * 68 + r] = qv.x; Qs[(dq + 1) * 68 + r] = qv.y;
    Qs[(dq + 2) * 68 + r] = qv.z; Qs[(dq + 3) * 68 + r] = qv.w;
    Ks[(dq + 0) * 68 + r] = kv.x; Ks[(dq + 1) * 68 + r] = kv.y;
    Ks[(dq + 2) * 68 + r] = kv.z; Ks[(dq + 3) * 68 + r] = kv.w;
  }
  __syncthreads();
  float acc[4][4] = {};
  #pragma unroll 4
  for (int d = 0; d < DAUG; d++) {
    float4 qv = *(const float4*)&Qs[d * 68 + ty * 4];
    float4 kv = *(const float4*)&Ks[d * 68 + tx * 4];
    acc[0][0] += qv.x * kv.x; acc[0][1] += qv.x * kv.y; acc[0][2] += qv.x * kv.z; acc[0][3] += qv.x * kv.w;
    acc[1][0] += qv.y * kv.x; acc[1][1] += qv.y * kv.y; acc[1][2] += qv.y * kv.z; acc[1][3] += qv.y * kv.w;
    acc[2][0] += qv.z * kv.x; acc[2][1] += qv.z * kv.y; acc[2][2] += qv.z * kv.z; acc[2][3] += qv.z * kv.w;
    acc[3][0] += qv.w * kv.x; acc[3][1] += qv.w * kv.y; acc[3][2] += qv.w * kv.z; acc[3][3] += qv.w * kv.w;
  }
  int nb = n0 + tx * 4;
  float4 pv = *(const float4*)&amask[b * SS + nb];
  #pragma unroll
  for (int i = 0; i < 4; i++) {
    int m = m0 + ty * 4 + i;
    float4 o;
    float v0 = acc[i][0] * pv.x - (1.f - pv.x) * NEGV; if (nb + 0 < m) v0 -= NEGV;
    float v1 = acc[i][1] * pv.y - (1.f - pv.y) * NEGV; if (nb + 1 < m) v1 -= NEGV;
    float v2 = acc[i][2] * pv.z - (1.f - pv.z) * NEGV; if (nb + 2 < m) v2 -= NEGV;
    float v3 = acc[i][3] * pv.w - (1.f - pv.w) * NEGV; if (nb + 3 < m) v3 -= NEGV;
    o.x = v0 * 0.125f; o.y = v1 * 0.125f; o.z = v2 * 0.125f; o.w = v3 * 0.125f;
    *(float4*)&out[((size_t)bz * SS + m) * SS + nb] = o;
  }
}

extern "C" void kernel_launch(void* const* d_in, const int* in_sizes, int n_in,
                              void* d_out, int out_size, void* d_ws, size_t ws_size,
                              hipStream_t stream) {
  const float* hidden  = (const float*)d_in[0];
  const float* amask   = (const float*)d_in[1];
  const int*   spans   = (const int*)d_in[2];
  const float* W1      = (const float*)d_in[3];
  const float* a_src1  = (const float*)d_in[4];
  const float* a_dst1  = (const float*)d_in[5];
  const float* b1      = (const float*)d_in[6];
  const float* ln_g    = (const float*)d_in[7];
  const float* ln_b    = (const float*)d_in[8];
  const float* W2      = (const float*)d_in[9];
  const float* a_src2  = (const float*)d_in[10];
  const float* a_dst2  = (const float*)d_in[11];
  const float* b2      = (const float*)d_in[12];
  const float* dense_W = (const float*)d_in[13];
  const float* dense_b = (const float*)d_in[14];
  const float* gc      = (const float*)d_in[15];
  const float* gs      = (const float*)d_in[16];
  const float* gw      = (const float*)d_in[17];
  const float* corr    = (const float*)d_in[18];

  float* ws    = (float*)d_ws;
  float* qk    = ws;                                    // B*S*1024      = 8,388,608
  float* Qa    = qk + (size_t)BB * SS * CDIM;           // B*T*S*80      = 5,242,880
  float* Ka    = Qa + (size_t)BB * TT * SS * DAUG;      // B*T*S*80      = 5,242,880
  float* nodes = Ka + (size_t)BB * TT * SS * DAUG;      // B*9*768       = 55,296
  float* cover = nodes + (size_t)BB * NNODES * HH;      // B*S           = 8,192
  float* E2    = cover + (size_t)BB * SS;               // B*1024        = 8,192
  float* outp  = (float*)d_out;

  k1_nodes<<<BB, 256, 0, stream>>>(hidden, spans, nodes, cover);
  k2_gat<<<BB, 256, 0, stream>>>(nodes, spans, W1, a_src1, a_dst1, b1, ln_g, ln_b,
                                 W2, a_src2, a_dst2, b2, dense_W, E2);
  k3_dense<<<dim3(CDIM / 64, (BB * SS) / 64), 256, 0, stream>>>(hidden, dense_W, dense_b,
                                                                cover, E2, qk);
  k4_ropeaug<<<(BB * TT * SS * 20) / 256, 256, 0, stream>>>(qk, spans, corr, gc, gs, gw, Qa, Ka);
  k5_logits<<<dim3(16, 16, BB * TT), 256, 0, stream>>>(Qa, Ka, amask, outp);
}

// Round 2
// 671.363 us; speedup vs baseline: 1.5403x; 1.5403x over previous
//
#include <hip/hip_runtime.h>
#include <cstdint>
#include <cstddef>

#define BB 8
#define SS 1024
#define HH 768
#define TT 8
#define DII 64
#define HIDD 128
#define KSP 8
#define NHEADS 2
#define NNODES 9
#define GDIM 256   // NHEADS*HIDD
#define CDIM 1024  // TT*2*DII == HH+GDIM
#define DAUGP 96   // 64 rope + 16 gauss + 16 zero pad (3 x 32-k MFMA slabs)
#define NEGV 1e12f

using bf16x8 = __attribute__((ext_vector_type(8))) __bf16;
using f32x4  = __attribute__((ext_vector_type(4))) float;

static __device__ inline unsigned short f2bf(float x) {
  union { float f; unsigned u; } v; v.f = x;
  unsigned r = v.u + 0x7fff + ((v.u >> 16) & 1);
  return (unsigned short)(r >> 16);
}

// ---------------- kc1: hidden fp32 -> bf16 (row-major [8192][768]) ---------------
__global__ void kc1_cvt_hidden(const float* __restrict__ hidden, unsigned short* __restrict__ hbf) {
  int idx = blockIdx.x * 256 + threadIdx.x;          // n/4 threads
  float4 v = *(const float4*)(hidden + (size_t)idx * 4);
  ushort4 o; o.x = f2bf(v.x); o.y = f2bf(v.y); o.z = f2bf(v.z); o.w = f2bf(v.w);
  *(ushort4*)(hbf + (size_t)idx * 4) = o;
}

// ---------------- kc2: dense_W[0:768][1024] -> WtopT[1024][768] bf16 -------------
__global__ void kc2_cvt_wtop(const float* __restrict__ dense_W, unsigned short* __restrict__ WtopT) {
  __shared__ float t[32][33];
  int k0 = blockIdx.x * 32, n0 = blockIdx.y * 32;
  int tid = threadIdx.x;
  int r = tid >> 3, c4 = (tid & 7) * 4;
  float4 v = *(const float4*)&dense_W[(size_t)(k0 + r) * CDIM + n0 + c4];
  t[r][c4 + 0] = v.x; t[r][c4 + 1] = v.y; t[r][c4 + 2] = v.z; t[r][c4 + 3] = v.w;
  __syncthreads();
  int ro = tid >> 3, co4 = (tid & 7) * 4;
  ushort4 o;
  o.x = f2bf(t[co4 + 0][ro]); o.y = f2bf(t[co4 + 1][ro]);
  o.z = f2bf(t[co4 + 2][ro]); o.w = f2bf(t[co4 + 3][ro]);
  *(ushort4*)&WtopT[(size_t)(n0 + ro) * HH + k0 + co4] = o;
}

// ---------------- k1a: cover + span means ----------------------------------------
__global__ void k1a_spans(const float* __restrict__ hidden, const int* __restrict__ spans,
                          float* __restrict__ nodes, float* __restrict__ cover) {
  int b = blockIdx.x, tid = threadIdx.x;
  __shared__ int sp[KSP * 3];
  if (tid < KSP * 3) sp[tid] = spans[b * KSP * 3 + tid];
  __syncthreads();
  for (int s = tid; s < SS; s += 256) {
    float c = 0.f;
    #pragma unroll
    for (int k = 0; k < KSP; k++)
      c += (s >= sp[k * 3] && s <= sp[k * 3 + 1]) ? 1.f : 0.f;
    cover[b * SS + s] = c;
  }
  const float* hb = hidden + (size_t)b * SS * HH;
  for (int k = 0; k < KSP; k++) {
    int st = sp[k * 3], en = sp[k * 3 + 1];
    float inv = 1.f / (float)(en - st + 1);
    for (int c = tid; c < HH; c += 256) {
      float a = 0.f;
      for (int s = st; s <= en; s++) a += hb[(size_t)s * HH + c];
      nodes[((size_t)b * NNODES + (k + 1)) * HH + c] = a * inv;
    }
  }
}

// ---------------- k1b/k1c: global mean (2-stage) ---------------------------------
__global__ void k1b_partial(const float* __restrict__ hidden, float* __restrict__ part) {
  int z = blockIdx.x, b = blockIdx.y, tid = threadIdx.x;
  const float* hb = hidden + (size_t)b * SS * HH;
  #pragma unroll
  for (int j = 0; j < 3; j++) {
    int c = tid + j * 256;
    float acc = 0.f;
    for (int r = z * 64; r < z * 64 + 64; r++) acc += hb[(size_t)r * HH + c];
    part[((size_t)b * 16 + z) * HH + c] = acc;
  }
}
__global__ void k1c_reduce(const float* __restrict__ part, float* __restrict__ nodes) {
  int b = blockIdx.x, tid = threadIdx.x;
  #pragma unroll
  for (int j = 0; j < 3; j++) {
    int c = tid + j * 256;
    float s = 0.f;
    for (int z = 0; z < 16; z++) s += part[((size_t)b * 16 + z) * HH + c];
    nodes[(size_t)b * NNODES * HH + c] = s / (float)SS;
  }
}

// ---------------- k2: two GAT layers + LN -> enh ---------------------------------
__global__ __launch_bounds__(256) void k2_gat(
    const float* __restrict__ nodes_g, const int* __restrict__ spans,
    const float* __restrict__ W1, const float* __restrict__ a_src1,
    const float* __restrict__ a_dst1, const float* __restrict__ b1,
    const float* __restrict__ ln_g, const float* __restrict__ ln_b,
    const float* __restrict__ W2, const float* __restrict__ a_src2,
    const float* __restrict__ a_dst2, const float* __restrict__ b2,
    float* __restrict__ enhg) {
  int b = blockIdx.x, tid = threadIdx.x;
  __shared__ float nod[NNODES * HH];
  __shared__ float hbuf[NNODES * GDIM];
  __shared__ float gbuf[NNODES * GDIM];
  __shared__ float asrc[NNODES * NHEADS], adst[NNODES * NHEADS];
  __shared__ float adjm[NNODES * NNODES];
  __shared__ float attn[NNODES * NNODES * NHEADS];
  __shared__ float mu_s[NNODES], rs_s[NNODES];
  __shared__ int sp[KSP * 3];
  if (tid < KSP * 3) sp[tid] = spans[b * KSP * 3 + tid];
  for (int i = tid; i < NNODES * HH; i += 256)
    nod[i] = nodes_g[(size_t)b * NNODES * HH + i];
  __syncthreads();
  {
    float acc[NNODES];
    #pragma unroll
    for (int n = 0; n < NNODES; n++) acc[n] = 0.f;
    for (int d = 0; d < HH; d++) {
      float w = W1[(size_t)d * GDIM + tid];
      #pragma unroll
      for (int n = 0; n < NNODES; n++) acc[n] += nod[n * HH + d] * w;
    }
    #pragma unroll
    for (int n = 0; n < NNODES; n++) hbuf[n * GDIM + tid] = acc[n];
  }
  if (tid < NNODES * NNODES) {
    int i = tid / NNODES, j = tid % NNODES;
    float a = (i == j) ? 1.f : 0.f;
    if (i > 0 && j == 0) a += 1.f;
    if (i == 0 && j > 0) a += 1.f;
    if (i > 0 && j > 0 && i != j) {
      int x = j - 1, y = i - 1;
      int sx = sp[x * 3], ex = sp[x * 3 + 1], sy = sp[y * 3], ey = sp[y * 3 + 1];
      bool same = (sx == sy) && (ex == ey);
      if (sx <= sy && ey <= ex && !same) a += 2.f;
    }
    adjm[tid] = a;
  }
  __syncthreads();
  if (tid < NNODES * NHEADS) {
    int n = tid >> 1, hd = tid & 1;
    float sa = 0.f, sd = 0.f;
    for (int f = 0; f < HIDD; f++) {
      float v = hbuf[n * GDIM + hd * HIDD + f];
      sa += v * a_src1[hd * HIDD + f];
      sd += v * a_dst1[hd * HIDD + f];
    }
    asrc[tid] = sa; adst[tid] = sd;
  }
  __syncthreads();
  if (tid < NNODES * NHEADS) {
    int d = tid >> 1, hd = tid & 1;
    float sc[NNODES]; float mx = -1e30f;
    for (int s2 = 0; s2 < NNODES; s2++) {
      float a = adjm[d * NNODES + s2]; float v;
      if (a > 0.f) {
        float e = adst[d * 2 + hd] + asrc[s2 * 2 + hd];
        e = (e > 0.f) ? e : 0.2f * e;
        v = e + __logf(a);
      } else v = -1e30f;
      sc[s2] = v; mx = fmaxf(mx, v);
    }
    float ssum = 0.f;
    for (int s2 = 0; s2 < NNODES; s2++) { float ex = __expf(sc[s2] - mx); sc[s2] = ex; ssum += ex; }
    float inv = 1.f / ssum;
    for (int s2 = 0; s2 < NNODES; s2++) attn[(d * NNODES + s2) * NHEADS + hd] = sc[s2] * inv;
  }
  __syncthreads();
  {
    int hd = tid >> 7;
    float bb = b1[tid];
    for (int d = 0; d < NNODES; d++) {
      float acc = bb;
      #pragma unroll
      for (int s2 = 0; s2 < NNODES; s2++)
        acc += attn[(d * NNODES + s2) * NHEADS + hd] * hbuf[s2 * GDIM + tid];
      gbuf[d * GDIM + tid] = fmaxf(acc, 0.f);
    }
  }
  __syncthreads();
  if (tid < NNODES) {
    float s1 = 0.f, s2v = 0.f;
    for (int o = 0; o < GDIM; o++) { float v = gbuf[tid * GDIM + o]; s1 += v; s2v += v * v; }
    float mu = s1 / (float)GDIM;
    float var = s2v / (float)GDIM - mu * mu;
    mu_s[tid] = mu; rs_s[tid] = rsqrtf(var + 1e-5f);
  }
  __syncthreads();
  {
    float g = ln_g[tid], bt = ln_b[tid];
    for (int d = 0; d < NNODES; d++)
      gbuf[d * GDIM + tid] = (gbuf[d * GDIM + tid] - mu_s[d]) * rs_s[d] * g + bt;
  }
  __syncthreads();
  {
    float acc[NNODES];
    #pragma unroll
    for (int n = 0; n < NNODES; n++) acc[n] = 0.f;
    for (int d = 0; d < GDIM; d++) {
      float w = W2[(size_t)d * GDIM + tid];
      #pragma unroll
      for (int n = 0; n < NNODES; n++) acc[n] += gbuf[n * GDIM + d] * w;
    }
    #pragma unroll
    for (int n = 0; n < NNODES; n++) hbuf[n * GDIM + tid] = acc[n];
  }
  __syncthreads();
  if (tid < NNODES * NHEADS) {
    int n = tid >> 1, hd = tid & 1;
    float sa = 0.f, sd = 0.f;
    for (int f = 0; f < HIDD; f++) {
      float v = hbuf[n * GDIM + hd * HIDD + f];
      sa += v * a_src2[hd * HIDD + f];
      sd += v * a_dst2[hd * HIDD + f];
    }
    asrc[tid] = sa; adst[tid] = sd;
  }
  __syncthreads();
  if (tid < NNODES * NHEADS) {
    int d = tid >> 1, hd = tid & 1;
    float sc[NNODES]; float mx = -1e30f;
    for (int s2 = 0; s2 < NNODES; s2++) {
      float a = adjm[d * NNODES + s2]; float v;
      if (a > 0.f) {
        float e = adst[d * 2 + hd] + asrc[s2 * 2 + hd];
        e = (e > 0.f) ? e : 0.2f * e;
        v = e + __logf(a);
      } else v = -1e30f;
      sc[s2] = v; mx = fmaxf(mx, v);
    }
    float ssum = 0.f;
    for (int s2 = 0; s2 < NNODES; s2++) { float ex = __expf(sc[s2] - mx); sc[s2] = ex; ssum += ex; }
    float inv = 1.f / ssum;
    for (int s2 = 0; s2 < NNODES; s2++) attn[(d * NNODES + s2) * NHEADS + hd] = sc[s2] * inv;
  }
  __syncthreads();
  {
    int hd = tid >> 7;
    float bb = b2[tid];
    float msum = 0.f;
    for (int d = 0; d < NNODES; d++) {
      float acc = bb;
      #pragma unroll
      for (int s2 = 0; s2 < NNODES; s2++)
        acc += attn[(d * NNODES + s2) * NHEADS + hd] * hbuf[s2 * GDIM + tid];
      msum += fmaxf(acc, 0.f);
    }
    enhg[b * GDIM + tid] = msum / 9.f;
  }
}

// ---------------- k2b: E2 = enh @ dense_W[768:1024] ------------------------------
__global__ void k2b_e2(const float* __restrict__ enhg, const float* __restrict__ dense_W,
                       float* __restrict__ E2) {
  int b = blockIdx.y, tid = threadIdx.x;
  int o = blockIdx.x * 256 + tid;
  __shared__ float eh[GDIM];
  eh[tid] = enhg[b * GDIM + tid];
  __syncthreads();
  float acc = 0.f;
  for (int d = 0; d < GDIM; d++)
    acc += eh[d] * dense_W[(size_t)(HH + d) * CDIM + o];
  E2[b * CDIM + o] = acc;
}

// ---------------- k3: qk = hidden @ Wtop (MFMA bf16) + cover*E2 + b --------------
__global__ __launch_bounds__(256) void k3_dense(
    const unsigned short* __restrict__ hbf, const unsigned short* __restrict__ WtopT,
    const float* __restrict__ dense_b, const float* __restrict__ cover,
    const float* __restrict__ E2, float* __restrict__ qk) {
  __shared__ unsigned short As[128 * 40];  // [m][kpad=40]
  __shared__ unsigned short Bs[128 * 40];  // [n][kpad=40]
  int tid = threadIdx.x;
  int n0 = blockIdx.x * 128, m0 = blockIdx.y * 128;
  int wave = tid >> 6, lane = tid & 63;
  int wr = wave >> 1, wc = wave & 1;
  int colL = lane & 15, quad = lane >> 4;
  f32x4 acc[4][4];
  #pragma unroll
  for (int i = 0; i < 4; i++)
    #pragma unroll
    for (int j = 0; j < 4; j++) { acc[i][j][0] = 0.f; acc[i][j][1] = 0.f; acc[i][j][2] = 0.f; acc[i][j][3] = 0.f; }
  for (int k0 = 0; k0 < HH; k0 += 32) {
    uint4 va[2], vb[2];
    #pragma unroll
    for (int it = 0; it < 2; it++) {
      int idx = tid + it * 256;           // 0..511
      int r = idx >> 2, seg = idx & 3;
      va[it] = *(const uint4*)(hbf + (size_t)(m0 + r) * HH + k0 + seg * 8);
      vb[it] = *(const uint4*)(WtopT + (size_t)(n0 + r) * HH + k0 + seg * 8);
    }
    __syncthreads();
    #pragma unroll
    for (int it = 0; it < 2; it++) {
      int idx = tid + it * 256;
      int r = idx >> 2, seg = idx & 3;
      *(uint4*)&As[r * 40 + seg * 8] = va[it];
      *(uint4*)&Bs[r * 40 + seg * 8] = vb[it];
    }
    __syncthreads();
    bf16x8 af[4], bf[4];
    #pragma unroll
    for (int tm = 0; tm < 4; tm++)
      af[tm] = *(const bf16x8*)&As[(wr * 64 + tm * 16 + colL) * 40 + quad * 8];
    #pragma unroll
    for (int tn = 0; tn < 4; tn++)
      bf[tn] = *(const bf16x8*)&Bs[(wc * 64 + tn * 16 + colL) * 40 + quad * 8];
    #pragma unroll
    for (int tm = 0; tm < 4; tm++)
      #pragma unroll
      for (int tn = 0; tn < 4; tn++)
        acc[tm][tn] = __builtin_amdgcn_mfma_f32_16x16x32_bf16(af[tm], bf[tn], acc[tm][tn], 0, 0, 0);
  }
  int b = m0 >> 10;
  #pragma unroll
  for (int tn = 0; tn < 4; tn++) {
    int col = n0 + wc * 64 + tn * 16 + colL;
    float e2 = E2[b * CDIM + col];
    float db = dense_b[col];
    #pragma unroll
    for (int tm = 0; tm < 4; tm++) {
      int rbase = m0 + wr * 64 + tm * 16 + quad * 4;
      #pragma unroll
      for (int r = 0; r < 4; r++) {
        int m = rbase + r;
        qk[(size_t)m * CDIM + col] = acc[tm][tn][r] + cover[m] * e2 + db;
      }
    }
  }
}

// ---------------- k4: RoPE + gauss -> Qa/Ka bf16 [bt][s][96] ---------------------
__global__ void k4_ropeaug(const float* __restrict__ qk, const int* __restrict__ spans,
                           const float* __restrict__ corr, const float* __restrict__ gc,
                           const float* __restrict__ gs, const float* __restrict__ gw,
                           unsigned short* __restrict__ Qa, unsigned short* __restrict__ Ka) {
  int tid = threadIdx.x;
  int g = tid >> 5, lane = tid & 31;
  int row = blockIdx.x * 8 + g;           // global (b,s) row
  int b = row >> 10, s = row & 1023;
  const float* qrow = qk + (size_t)row * CDIM;
  const float LOG1E4_32 = 0.28782313662425576f;  // ln(10000)/32
  #pragma unroll
  for (int it = 0; it < 8; it++) {
    int cbase = it * 128 + lane * 4;
    float4 v = *(const float4*)(qrow + cbase);
    int t = cbase >> 7;
    int d = cbase & 127;
    int dd = d & 63;
    int i0 = dd >> 1;
    float inv0 = __expf(-(float)i0 * LOG1E4_32);
    float inv1 = __expf(-(float)(i0 + 1) * LOG1E4_32);
    float s0, c0, s1, c1;
    __sincosf((float)s * inv0, &s0, &c0);
    __sincosf((float)s * inv1, &s1, &c1);
    float o0 = v.x * c0 - v.y * s0;
    float o1 = v.y * c0 + v.x * s0;
    float o2 = v.z * c1 - v.w * s1;
    float o3 = v.w * c1 + v.z * s1;
    ushort4 w; w.x = f2bf(o0); w.y = f2bf(o1); w.z = f2bf(o2); w.w = f2bf(o3);
    size_t base = ((size_t)(b * TT + t) * SS + s) * DAUGP;
    if (d < 64) *(ushort4*)(Qa + base + dd) = w;
    else        *(ushort4*)(Ka + base + dd) = w;
  }
  // gauss dims 64..79 and zero pad 80..95
  int j = lane & 15;
  int kp = j >> 1, c = j & 1;
  int st = spans[(b * KSP + kp) * 3 + 0];
  int en = spans[(b * KSP + kp) * 3 + 1];
  int et = spans[(b * KSP + kp) * 3 + 2];
  float sig = gs[c], wgt = gw[c], ce = gc[c];
  if (lane < 16) {
    float dx = ((float)(s - st) - ce) / sig;
    float e = wgt * __expf(-0.5f * dx * dx);
    #pragma unroll
    for (int t = 0; t < TT; t++) {
      size_t base = ((size_t)(b * TT + t) * SS + s) * DAUGP;
      Qa[base + 64 + j] = f2bf(corr[et * TT + t] * e);
      Qa[base + 80 + j] = 0;
    }
  } else {
    float dx = ((float)(s - en) - ce) / sig;
    unsigned short bv = f2bf(wgt * __expf(-0.5f * dx * dx));
    #pragma unroll
    for (int t = 0; t < TT; t++) {
      size_t base = ((size_t)(b * TT + t) * SS + s) * DAUGP;
      Ka[base + 64 + j] = bv;
      Ka[base + 80 + j] = 0;
    }
  }
}

// ---------------- k5: logits = Qa @ Ka^T (MFMA bf16) + mask ----------------------
__global__ __launch_bounds__(256) void k5_logits(
    const unsigned short* __restrict__ Qa, const unsigned short* __restrict__ Ka,
    const float* __restrict__ amask, float* __restrict__ out) {
  int bz = blockIdx.z; int b = bz >> 3;
  int n0 = blockIdx.x * 128, m0 = blockIdx.y * 128;
  int tid = threadIdx.x;
  if (n0 + 127 < m0) {
    // strictly below diagonal: write masked constant
    int r0 = tid >> 5, c4 = (tid & 31) * 4;
    float4 pv = *(const float4*)&amask[b * SS + n0 + c4];
    float4 o;
    o.x = (-(1.f - pv.x) * NEGV - NEGV) * 0.125f;
    o.y = (-(1.f - pv.y) * NEGV - NEGV) * 0.125f;
    o.z = (-(1.f - pv.z) * NEGV - NEGV) * 0.125f;
    o.w = (-(1.f - pv.w) * NEGV - NEGV) * 0.125f;
    for (int r = r0; r < 128; r += 8)
      *(float4*)&out[((size_t)bz * SS + m0 + r) * SS + n0 + c4] = o;
    return;
  }
  __shared__ unsigned short Qs[128 * 104];   // [m][kpad=104]
  __shared__ unsigned short Ks[128 * 104];   // [n][kpad=104]
  const unsigned short* Qrow = Qa + ((size_t)bz * SS + m0) * DAUGP;
  const unsigned short* Krow = Ka + ((size_t)bz * SS + n0) * DAUGP;
  #pragma unroll
  for (int it = 0; it < 6; it++) {
    int idx = tid + it * 256;                // 0..1535
    int r = idx / 12, seg = idx % 12;
    uint4 vq = *(const uint4*)(Qrow + (size_t)r * DAUGP + seg * 8);
    uint4 vk = *(const uint4*)(Krow + (size_t)r * DAUGP + seg * 8);
    *(uint4*)&Qs[r * 104 + seg * 8] = vq;
    *(uint4*)&Ks[r * 104 + seg * 8] = vk;
  }
  __syncthreads();
  int wave = tid >> 6, lane = tid & 63;
  int wr = wave >> 1, wc = wave & 1;
  int colL = lane & 15, quad = lane >> 4;
  f32x4 acc[4][4];
  #pragma unroll
  for (int i = 0; i < 4; i++)
    #pragma unroll
    for (int j = 0; j < 4; j++) { acc[i][j][0] = 0.f; acc[i][j][1] = 0.f; acc[i][j][2] = 0.f; acc[i][j][3] = 0.f; }
  #pragma unroll
  for (int ks = 0; ks < 3; ks++) {
    bf16x8 af[4], bf[4];
    #pragma unroll
    for (int tm = 0; tm < 4; tm++)
      af[tm] = *(const bf16x8*)&Qs[(wr * 64 + tm * 16 + colL) * 104 + ks * 32 + quad * 8];
    #pragma unroll
    for (int tn = 0; tn < 4; tn++)
      bf[tn] = *(const bf16x8*)&Ks[(wc * 64 + tn * 16 + colL) * 104 + ks * 32 + quad * 8];
    #pragma unroll
    for (int tm = 0; tm < 4; tm++)
      #pragma unroll
      for (int tn = 0; tn < 4; tn++)
        acc[tm][tn] = __builtin_amdgcn_mfma_f32_16x16x32_bf16(af[tm], bf[tn], acc[tm][tn], 0, 0, 0);
  }
  #pragma unroll
  for (int tn = 0; tn < 4; tn++) {
    int col = n0 + wc * 64 + tn * 16 + colL;
    float p = amask[b * SS + col];
    float negp = -(1.f - p) * NEGV;
    #pragma unroll
    for (int tm = 0; tm < 4; tm++) {
      int rbase = m0 + wr * 64 + tm * 16 + quad * 4;
      #pragma unroll
      for (int r = 0; r < 4; r++) {
        int m = rbase + r;
        float v = acc[tm][tn][r] * p + negp;
        if (col < m) v -= NEGV;
        out[((size_t)bz * SS + m) * SS + col] = v * 0.125f;
      }
    }
  }
}

extern "C" void kernel_launch(void* const* d_in, const int* in_sizes, int n_in,
                              void* d_out, int out_size, void* d_ws, size_t ws_size,
                              hipStream_t stream) {
  const float* hidden  = (const float*)d_in[0];
  const float* amask   = (const float*)d_in[1];
  const int*   spans   = (const int*)d_in[2];
  const float* W1      = (const float*)d_in[3];
  const float* a_src1  = (const float*)d_in[4];
  const float* a_dst1  = (const float*)d_in[5];
  const float* b1      = (const float*)d_in[6];
  const float* ln_g    = (const float*)d_in[7];
  const float* ln_b    = (const float*)d_in[8];
  const float* W2      = (const float*)d_in[9];
  const float* a_src2  = (const float*)d_in[10];
  const float* a_dst2  = (const float*)d_in[11];
  const float* b2      = (const float*)d_in[12];
  const float* dense_W = (const float*)d_in[13];
  const float* dense_b = (const float*)d_in[14];
  const float* gc      = (const float*)d_in[15];
  const float* gs      = (const float*)d_in[16];
  const float* gw      = (const float*)d_in[17];
  const float* corr    = (const float*)d_in[18];

  char* wsb = (char*)d_ws;
  float* qk            = (float*)wsb;                         wsb += (size_t)BB * SS * CDIM * 4;        // 33.5 MB
  unsigned short* hbf  = (unsigned short*)wsb;                wsb += (size_t)BB * SS * HH * 2;          // 12.6 MB
  unsigned short* WtopT= (unsigned short*)wsb;                wsb += (size_t)CDIM * HH * 2;             // 1.57 MB
  unsigned short* Qa   = (unsigned short*)wsb;                wsb += (size_t)BB * TT * SS * DAUGP * 2;  // 12.6 MB
  unsigned short* Ka   = (unsigned short*)wsb;                wsb += (size_t)BB * TT * SS * DAUGP * 2;  // 12.6 MB
  float* nodes         = (float*)wsb;                         wsb += (size_t)BB * NNODES * HH * 4;
  float* cover         = (float*)wsb;                         wsb += (size_t)BB * SS * 4;
  float* E2            = (float*)wsb;                         wsb += (size_t)BB * CDIM * 4;
  float* enhg          = (float*)wsb;                         wsb += (size_t)BB * GDIM * 4;
  float* part          = (float*)wsb;                         wsb += (size_t)BB * 16 * HH * 4;
  float* outp = (float*)d_out;

  kc1_cvt_hidden<<<(BB * SS * HH / 4) / 256, 256, 0, stream>>>(hidden, hbf);
  kc2_cvt_wtop<<<dim3(HH / 32, CDIM / 32), 256, 0, stream>>>(dense_W, WtopT);
  k1a_spans<<<BB, 256, 0, stream>>>(hidden, spans, nodes, cover);
  k1b_partial<<<dim3(16, BB), 256, 0, stream>>>(hidden, part);
  k1c_reduce<<<BB, 256, 0, stream>>>(part, nodes);
  k2_gat<<<BB, 256, 0, stream>>>(nodes, spans, W1, a_src1, a_dst1, b1, ln_g, ln_b,
                                 W2, a_src2, a_dst2, b2, enhg);
  k2b_e2<<<dim3(CDIM / 256, BB), 256, 0, stream>>>(enhg, dense_W, E2);
  k3_dense<<<dim3(CDIM / 128, (BB * SS) / 128), 256, 0, stream>>>(hbf, WtopT, dense_b,
                                                                  cover, E2, qk);
  k4_ropeaug<<<(BB * SS) / 8, 256, 0, stream>>>(qk, spans, corr, gc, gs, gw, Qa, Ka);
  k5_logits<<<dim3(8, 8, BB * TT), 256, 0, stream>>>(Qa, Ka, amask, outp);
}